// Round 7
// baseline (188.437 us; speedup 1.0000x reference)
//
#include <hip/hip_runtime.h>
#include <hip/hip_fp16.h>

#define N_NODES 100000
#define N_EDGES 1600000
// Y2: duplicated-pair layout [n][ku 0..3][kv' 0..2][2 cells x 16 f] fp16
//  block (ku,kv') = 64B = concat(cell(ku,kv'), cell(ku,kv'+1))
#define Y2_HALFS_PER_NODE 384                  // 4*3*32
#define Y2_BYTES ((size_t)N_NODES * Y2_HALFS_PER_NODE * 2)   // 76.8 MB
#define ACC_ELEMS ((size_t)N_NODES * 16)
#define ACC_BYTES (ACC_ELEMS * 2)              // 3.2 MB
#define WS_NEEDED (Y2_BYTES + ACC_BYTES)       // 80 MB

__global__ __launch_bounds__(256) void zero_acc_kernel(uint4* __restrict__ p, int n) {
    int i = blockIdx.x * 256 + threadIdx.x;
    if (i < n) p[i] = make_uint4(0, 0, 0, 0);
}

// ---- Stage 1: Y2 blocks from x @ W ----
// 16 nodes per wave -> 6250 waves (R6 had only 1564 waves: latency-starved).
// Lane: k = lane>>2 (cell), fq = lane&3 (feature quad). W column in registers.
// x staged via one coalesced float4 per lane; reads are same-address broadcast.
__global__ __launch_bounds__(256) void stage1_xw_pair(
    const float* __restrict__ x,       // [N_NODES,16]
    const float* __restrict__ w,       // [16][16][16] = [k][i][f]
    unsigned short* __restrict__ Y2)
{
    __shared__ float4 xls[4][64];
    const int lane = threadIdx.x & 63;
    const int wid  = threadIdx.x >> 6;
    const int k  = lane >> 2;
    const int fq = lane & 3;
    const int ku = k >> 2, kv = k & 3;
    const int batch = blockIdx.x * 4 + wid;
    if (batch >= N_NODES / 16) return;          // no barriers used below
    const int base = batch * 16;

    float4 wr[16];
#pragma unroll
    for (int i = 0; i < 16; ++i)
        wr[i] = *(const float4*)(w + k * 256 + i * 16 + fq * 4);

    xls[wid][lane] = ((const float4*)(x + (size_t)base * 16))[lane];
    __builtin_amdgcn_s_waitcnt(0);              // drain own LDS writes (wave-private)

    // destination half-offsets within the node row for this cell (ku,kv):
    //  low half of block (ku,kv)   if kv<=2 ; high half of block (ku,kv-1) if kv>=1
    const int off_lo = (ku * 3 + kv) * 32 + fq * 4;
    const int off_hi = (ku * 3 + (kv - 1)) * 32 + 16 + fq * 4;

#pragma unroll 1
    for (int j = 0; j < 16; ++j) {
        float xs[16];
#pragma unroll
        for (int q = 0; q < 4; ++q) {
            float4 t4 = xls[wid][j * 4 + q];    // broadcast read
            xs[4*q+0] = t4.x; xs[4*q+1] = t4.y; xs[4*q+2] = t4.z; xs[4*q+3] = t4.w;
        }
        float4 acc = make_float4(0.f, 0.f, 0.f, 0.f);
#pragma unroll
        for (int i = 0; i < 16; ++i) {
            acc.x += xs[i] * wr[i].x; acc.y += xs[i] * wr[i].y;
            acc.z += xs[i] * wr[i].z; acc.w += xs[i] * wr[i].w;
        }
        __half2 h0 = __floats2half2_rn(acc.x, acc.y);
        __half2 h1 = __floats2half2_rn(acc.z, acc.w);
        uint2 o = make_uint2(*(unsigned int*)&h0, *(unsigned int*)&h1);
        unsigned short* yrow = Y2 + (size_t)(base + j) * Y2_HALFS_PER_NODE;
        if (kv <= 2) *(uint2*)(yrow + off_lo) = o;
        if (kv >= 1) *(uint2*)(yrow + off_hi) = o;
    }
}

// ---- Stage 2: 16 lanes/edge, two aligned fully-used 64B block loads ----
// Lane l: uint from block A=(iu,iv) and B=(iu+1,iv). l<8 holds cell kv=iv
// (features 2l,2l+1), l>=8 holds cell iv+1. shfl_xor(8) swaps cell halves so
// every lane forms msg for feature pair p=l&7; lanes l<8 issue the pk atomic
// (8 contiguous 4B per edge = dense 32B sector, R6's good pattern).
__global__ __launch_bounds__(256) void stage2_pair(
    const int*   __restrict__ edge_index,
    const float* __restrict__ edge_attr,
    const unsigned short* __restrict__ Y2,
    __half2*     __restrict__ acc)             // [N_NODES][8] f16x2, pre-zeroed
{
    const int g = blockIdx.x * 256 + threadIdx.x;
    const int e = g >> 4;
    const int l = g & 15;

    const int row = edge_index[e];
    const int col = edge_index[N_EDGES + e];
    const float2 attr = ((const float2*)edge_attr)[e];

    float fu = (attr.x + 1.0f) * 1.5f;
    int iu = (int)fu; iu = iu < 0 ? 0 : (iu > 2 ? 2 : iu);
    const float wu1 = fu - (float)iu;
    const float wu0 = 1.0f - wu1;

    float fv = (attr.y + 1.0f) * 1.5f;
    int iv = (int)fv; iv = iv < 0 ? 0 : (iv > 2 ? 2 : iv);
    const float wv1 = fv - (float)iv;
    const float wv0 = 1.0f - wv1;

    const float t00 = wu0 * wv0, t01 = wu0 * wv1;
    const float t10 = wu1 * wv0, t11 = wu1 * wv1;

    const unsigned int* yrow = (const unsigned int*)(Y2 + (size_t)col * Y2_HALFS_PER_NODE);
    const unsigned int uA = yrow[(iu       * 3 + iv) * 16 + l];
    const unsigned int uB = yrow[((iu + 1) * 3 + iv) * 16 + l];
    const unsigned int uA2 = __shfl_xor((int)uA, 8);
    const unsigned int uB2 = __shfl_xor((int)uB, 8);

    const bool lowhalf = (l < 8);
    const float tAo = lowhalf ? t00 : t01, tAp = lowhalf ? t01 : t00;
    const float tBo = lowhalf ? t10 : t11, tBp = lowhalf ? t11 : t10;

    const float2 fAo = __half22float2(*(const __half2*)&uA);
    const float2 fAp = __half22float2(*(const __half2*)&uA2);
    const float2 fBo = __half22float2(*(const __half2*)&uB);
    const float2 fBp = __half22float2(*(const __half2*)&uB2);

    const float m0 = tAo * fAo.x + tAp * fAp.x + tBo * fBo.x + tBp * fBp.x;
    const float m1 = tAo * fAo.y + tAp * fAp.y + tBo * fBo.y + tBp * fBp.y;

    if (lowhalf)
        unsafeAtomicAdd(acc + (size_t)row * 8 + l, __floats2half2_rn(m0, m1));
}

__global__ __launch_bounds__(256) void convert_kernel(
    const __half2* __restrict__ acc, float2* __restrict__ out, int n2) {
    int i = blockIdx.x * 256 + threadIdx.x;
    if (i < n2) out[i] = __half22float2(acc[i]);
}

// ---------------- Fallback (R2, self-contained) ----------------
__global__ __launch_bounds__(256) void zero_out_kernel(float4* __restrict__ out, int n4) {
    int i = blockIdx.x * 256 + threadIdx.x;
    if (i < n4) out[i] = make_float4(0.f, 0.f, 0.f, 0.f);
}
#define FSLAB 260
__global__ __launch_bounds__(256) void basis_conv_edges(
    const float* __restrict__ x, const int* __restrict__ edge_index,
    const float* __restrict__ edge_attr, const float* __restrict__ weight,
    float* __restrict__ out)
{
    __shared__ float wl[16 * FSLAB];
    for (int idx = threadIdx.x; idx < 4096; idx += 256) {
        const int f = idx & 15, i = (idx >> 4) & 15, k = idx >> 8;
        wl[f * FSLAB + k * 16 + i] = weight[idx];
    }
    __syncthreads();
    const int f = threadIdx.x & 15, s = threadIdx.x >> 4;
    const int ebase = blockIdx.x * 256;
#pragma unroll 1
    for (int it = 0; it < 16; ++it) {
        const int e = ebase + it * 16 + s;
        const int row = edge_index[e];
        const int col = edge_index[N_EDGES + e];
        const float2 attr = ((const float2*)edge_attr)[e];
        float fu = (attr.x + 1.0f) * 1.5f;
        int iu = (int)fu; iu = iu < 0 ? 0 : (iu > 2 ? 2 : iu);
        const float wu1 = fu - (float)iu, wu0 = 1.0f - wu1;
        float fv = (attr.y + 1.0f) * 1.5f;
        int iv = (int)fv; iv = iv < 0 ? 0 : (iv > 2 ? 2 : iv);
        const float wv1 = fv - (float)iv, wv0 = 1.0f - wv1;
        const int k0 = iu * 4 + iv;
        int kb[4] = {k0, k0 + 1, k0 + 4, k0 + 5};
        float tw[4] = {wu0 * wv0, wu0 * wv1, wu1 * wv0, wu1 * wv1};
        const float4* xv = (const float4*)(x + (size_t)col * 16);
        float xs[16];
#pragma unroll
        for (int q = 0; q < 4; ++q) {
            float4 t4 = xv[q];
            xs[4*q+0]=t4.x; xs[4*q+1]=t4.y; xs[4*q+2]=t4.z; xs[4*q+3]=t4.w;
        }
        float msg = 0.0f;
#pragma unroll
        for (int p = 0; p < 4; ++p) {
            const float t = tw[p];
            const float4* wp = (const float4*)&wl[f * FSLAB + kb[p] * 16];
#pragma unroll
            for (int i4 = 0; i4 < 4; ++i4) {
                const float4 w = wp[i4];
                msg += t * (xs[4*i4+0]*w.x + xs[4*i4+1]*w.y + xs[4*i4+2]*w.z + xs[4*i4+3]*w.w);
            }
        }
        unsafeAtomicAdd(out + (size_t)row * 16 + f, msg);
    }
}

extern "C" void kernel_launch(void* const* d_in, const int* in_sizes, int n_in,
                              void* d_out, int out_size, void* d_ws, size_t ws_size,
                              hipStream_t stream) {
    const float* x  = (const float*)d_in[0];
    const int*   ei = (const int*)d_in[1];
    const float* ea = (const float*)d_in[2];
    const float* w  = (const float*)d_in[3];
    float* out = (float*)d_out;

    if (ws_size >= WS_NEEDED) {
        unsigned short* Y2 = (unsigned short*)d_ws;
        __half2* acc = (__half2*)((char*)d_ws + Y2_BYTES);

        const int nacc16 = (int)(ACC_BYTES / 16);
        zero_acc_kernel<<<(nacc16 + 255) / 256, 256, 0, stream>>>((uint4*)acc, nacc16);

        const int batches = N_NODES / 16;          // 6250
        stage1_xw_pair<<<(batches + 3) / 4, 256, 0, stream>>>(x, w, Y2);

        stage2_pair<<<(N_EDGES * 16) / 256, 256, 0, stream>>>(ei, ea, Y2, acc);

        const int n2 = (int)ACC_ELEMS / 2;
        convert_kernel<<<(n2 + 255) / 256, 256, 0, stream>>>(acc, (float2*)out, n2);
    } else {
        const int n4 = out_size / 4;
        zero_out_kernel<<<(n4 + 255) / 256, 256, 0, stream>>>((float4*)out, n4);
        basis_conv_edges<<<N_EDGES / 256, 256, 0, stream>>>(x, ei, ea, w, out);
    }
}